// Round 4
// baseline (827.907 us; speedup 1.0000x reference)
//
#include <hip/hip_runtime.h>

#define H   128
#define H2  256
#define NG  256
#define NT  40
#define NF  9

typedef __attribute__((ext_vector_type(8))) short short8;
typedef __attribute__((ext_vector_type(4))) float f32x4;

#define MFMA16(a, b, c) __builtin_amdgcn_mfma_f32_16x16x32_bf16(a, b, c, 0, 0, 0)

// float -> bf16 hi + bf16 lo (RNE both), x ~= hi + lo with ~2^-16 rel error
__device__ __forceinline__ void f2bf_hilo(float x, unsigned short& hi, unsigned short& lo) {
  unsigned u = __float_as_uint(x);
  unsigned hh = (u + 0x7FFFu + ((u >> 16) & 1u)) >> 16;
  float hf = __uint_as_float(hh << 16);
  float r = x - hf;
  unsigned v = __float_as_uint(r);
  unsigned ll = (v + 0x7FFFu + ((v >> 16) & 1u)) >> 16;
  hi = (unsigned short)hh;
  lo = (unsigned short)ll;
}

__device__ __forceinline__ void cvt8(float4 a, float4 b, short8& hi, short8& lo) {
  float xs[8] = {a.x, a.y, a.z, a.w, b.x, b.y, b.z, b.w};
#pragma unroll
  for (int j = 0; j < 8; j++) {
    unsigned short h, l;
    f2bf_hilo(xs[j], h, l);
    hi[j] = (short)h;
    lo[j] = (short)l;
  }
}

// ---------------- h0 = node_emb[x] ----------------
__global__ void k_h0(const int* __restrict__ x, const float* __restrict__ emb,
                     float* __restrict__ h, int N) {
  int i = blockIdx.x * blockDim.x + threadIdx.x;
  if (i >= N * 32) return;
  int v = i >> 5, q = i & 31;
  ((float4*)h)[i] = ((const float4*)emb)[x[v] * 32 + q];
}

// ---------------- degree only ----------------
__global__ void k_deg(const int* __restrict__ ei, unsigned* __restrict__ deg, int E) {
  int e = blockIdx.x * blockDim.x + threadIdx.x;
  if (e >= E) return;
  atomicAdd(&deg[ei[e]], 1u);
}

// ---------------- exclusive scan of deg -> off, cur ----------------
__global__ __launch_bounds__(1024) void k_scan(const unsigned* __restrict__ deg,
                                               unsigned* __restrict__ off,
                                               unsigned* __restrict__ cur, int N) {
  __shared__ unsigned wsum[16];
  __shared__ unsigned wpre[16];
  __shared__ unsigned s_run;
  int tid = threadIdx.x;
  int lane = tid & 63, wv = tid >> 6;
  if (tid == 0) s_run = 0u;
  __syncthreads();
  for (int base = 0; base < N; base += 4096) {
    int i0 = base + tid * 4;
    unsigned v0 = 0, v1 = 0, v2 = 0, v3 = 0;
    if (i0 + 0 < N) v0 = deg[i0 + 0];
    if (i0 + 1 < N) v1 = deg[i0 + 1];
    if (i0 + 2 < N) v2 = deg[i0 + 2];
    if (i0 + 3 < N) v3 = deg[i0 + 3];
    unsigned tsum = v0 + v1 + v2 + v3;
    unsigned sc = tsum;
#pragma unroll
    for (int d = 1; d < 64; d <<= 1) {
      unsigned t = __shfl_up(sc, d);
      if (lane >= d) sc += t;
    }
    if (lane == 63) wsum[wv] = sc;
    __syncthreads();
    if (wv == 0 && lane < 16) {
      unsigned xv = wsum[lane];
#pragma unroll
      for (int d = 1; d < 16; d <<= 1) {
        unsigned t = __shfl_up(xv, d);
        if (lane >= d) xv += t;
      }
      wpre[lane] = xv;
    }
    __syncthreads();
    unsigned excl = s_run + (wv ? wpre[wv - 1] : 0u) + (sc - tsum);
    unsigned p1 = excl + v0, p2 = p1 + v1, p3 = p2 + v2;
    if (i0 + 0 < N) { off[i0 + 0] = excl; cur[i0 + 0] = excl; }
    if (i0 + 1 < N) { off[i0 + 1] = p1;   cur[i0 + 1] = p1; }
    if (i0 + 2 < N) { off[i0 + 2] = p2;   cur[i0 + 2] = p2; }
    if (i0 + 3 < N) { off[i0 + 3] = p3;   cur[i0 + 3] = p3; }
    __syncthreads();
    if (tid == 0) s_run += wpre[15];
  }
  if (tid == 0) off[N] = s_run;
}

// ---------------- scatter edge src + edge id into CSR ----------------
__global__ void k_scatter(const int* __restrict__ ei, unsigned* __restrict__ cur,
                          int* __restrict__ csrc, int* __restrict__ ceid, int E) {
  int e = blockIdx.x * blockDim.x + threadIdx.x;
  if (e >= E) return;
  int dst = ei[e], src = ei[E + e];
  unsigned pos = atomicAdd(&cur[dst], 1u);
  csrc[pos] = src;
  ceid[pos] = e;
}

// ---------------- S[v] = sum of ea rows of incoming edges ----------------
__global__ __launch_bounds__(256) void k_S(const float* __restrict__ ea,
    const unsigned* __restrict__ off, const int* __restrict__ ceid,
    float* __restrict__ S, int N) {
  int lane = threadIdx.x & 63;
  int wv = threadIdx.x >> 6;
  int sub = lane & 7;
  int v = blockIdx.x * 32 + wv * 8 + (lane >> 3);
  if (v >= N) return;
  unsigned o = off[v], e = off[v + 1];
  float acc[NF];
#pragma unroll
  for (int f = 0; f < NF; f++) acc[f] = 0.f;
  for (unsigned i = o + sub; i < e; i += 8) {
    const float* a = ea + (size_t)ceid[i] * NF;
#pragma unroll
    for (int f = 0; f < NF; f++) acc[f] += a[f];
  }
#pragma unroll
  for (int d = 1; d < 8; d <<= 1)
#pragma unroll
    for (int f = 0; f < NF; f++) acc[f] += __shfl_xor(acc[f], d);
  if (sub == 0) {
#pragma unroll
    for (int f = 0; f < NF; f++) S[(size_t)v * NF + f] = acc[f];
  }
}

// ---------------- hsum[v] = h[v] + sum_{incoming} h[src] ----------------
__global__ __launch_bounds__(256) void k_gather(const float* __restrict__ h,
    const unsigned* __restrict__ off, const int* __restrict__ csrc,
    float* __restrict__ hs, int N) {
  int v = blockIdx.x * 4 + (threadIdx.x >> 6);
  int lane = threadIdx.x & 63;
  if (v >= N) return;
  unsigned o = off[v], e = off[v + 1];
  const float2* hp = (const float2*)h;
  float2 acc = hp[(size_t)v * 64 + lane];
  for (unsigned i = o; i < e; i++) {
    int s = csrc[i];
    float2 t = hp[(size_t)s * 64 + lane];
    acc.x += t.x; acc.y += t.y;
  }
  ((float2*)hs)[(size_t)v * 64 + lane] = acc;
}

// ---------------- per-layer: build fragment-ordered bf16 hi/lo B' (160x256) + BN consts ----------------
// B' rows: 0-127 w1_top, 128-136 M=enc_w@w1_bot, 137 u=enc_b@w1_bot, 138 K0, 139-159 zero
// frag idx for (k,c): ks=k>>5, ct=c>>4, lane=((k&31)>>3)*16+(c&15), j=k&7 ->
//   ((ks*16+ct)*64+lane)*8+j
__global__ void k_prepA(const float* __restrict__ enc_w, const float* __restrict__ enc_b,
                        const float* __restrict__ w1, const float* __restrict__ b1,
                        const float* __restrict__ gamma, const float* __restrict__ beta,
                        const float* __restrict__ mean, const float* __restrict__ var,
                        const int* __restrict__ sli, const int* __restrict__ slt,
                        unsigned short* __restrict__ BAhi, unsigned short* __restrict__ BAlo,
                        float* __restrict__ cc) {
  int c = threadIdx.x;  // 256
  float m[NF];
  float u = 0.f;
#pragma unroll
  for (int f = 0; f < NF; f++) m[f] = 0.f;
  for (int k = 0; k < H; k++) {
    float wv = w1[(size_t)(H + k) * H2 + c];
#pragma unroll
    for (int f = 0; f < NF; f++) m[f] += enc_w[f * H + k] * wv;
    u += enc_b[k] * wv;
  }
  float k0 = (float)(*slt) * m[*sli] + u + b1[c];
  float scv = gamma[c] * rsqrtf(var[c] + 1e-5f);
  cc[c] = scv;
  cc[H2 + c] = beta[c] - mean[c] * scv;
  int ct = c >> 4, cl = c & 15;
  for (int k = 0; k < 160; k++) {
    float val;
    if (k < 128)      val = w1[(size_t)k * H2 + c];
    else if (k < 137) val = m[k - 128];
    else if (k == 137) val = u;
    else if (k == 138) val = k0;
    else              val = 0.f;
    unsigned short h, l;
    f2bf_hilo(val, h, l);
    int ks = k >> 5, kr = k & 31;
    int lane = (kr >> 3) * 16 + cl, j = kr & 7;
    size_t idx = ((size_t)((ks * 16 + ct) * 64 + lane)) * 8 + j;
    BAhi[idx] = h;
    BAlo[idx] = l;
  }
}

// ---------------- per-layer: fragment-ordered bf16 hi/lo of w2 (256x128) ----------------
__global__ void k_prepB2(const float* __restrict__ w2,
                         unsigned short* __restrict__ BBhi, unsigned short* __restrict__ BBlo) {
  int t = threadIdx.x;  // 256
  int c = t & 127, half = t >> 7;
  int ct = c >> 4, cl = c & 15;
  for (int kk = 0; kk < 128; kk++) {
    int k = half * 128 + kk;
    float val = w2[(size_t)k * H + c];
    unsigned short h, l;
    f2bf_hilo(val, h, l);
    int ks = k >> 5, kr = k & 31;
    int lane = (kr >> 3) * 16 + cl, j = kr & 7;
    size_t idx = ((size_t)((ks * 8 + ct) * 64 + lane)) * 8 + j;
    BBhi[idx] = h;
    BBlo[idx] = l;
  }
}

// ---------------- fused MFMA GIN layer ----------------
// Phase A: z[32][256] = relu(BN([hs|S|deg|1] @ B'))   (3-term bf16 hi/lo MFMA)
// Phase B: out[32][128] = z @ w2 + b2                 (3-term bf16 hi/lo MFMA)
__global__ __launch_bounds__(256) void k_layer(
    const float* __restrict__ hs, const float* __restrict__ S,
    const unsigned* __restrict__ deg,
    const unsigned short* __restrict__ BAhi, const unsigned short* __restrict__ BAlo,
    const unsigned short* __restrict__ BBhi, const unsigned short* __restrict__ BBlo,
    const float* __restrict__ cc, const float* __restrict__ b2,
    float* __restrict__ out, const int* __restrict__ batch,
    int N, int relu_out, int pool) {
  __shared__ float ext[32][36];                 // cols: 0-8 S, 9 deg, 10 one, rest 0
  __shared__ unsigned short zhi[32 * 256];      // XOR-swizzled bf16 hi plane
  __shared__ unsigned short zlo[32 * 256];      // XOR-swizzled bf16 lo plane
  int tid = threadIdx.x;
  int row0 = blockIdx.x * 32;

  for (int i = tid; i < 32 * 36; i += 256) {
    int r = i / 36, c2 = i - r * 36;
    int v = row0 + r;
    float val = 0.f;
    if (v < N) {
      if (c2 < NF) val = S[(size_t)v * NF + c2];
      else if (c2 == 9) val = (float)deg[v];
      else if (c2 == 10) val = 1.0f;
    }
    ext[r][c2] = val;
  }
  __syncthreads();

  int l = tid & 63, wv = tid >> 6;
  int rowoff = (wv >> 1) * 16;   // which 16-row half
  int ctoffA = (wv & 1) * 8;     // phase A col-tile offset (of 16)
  int lr = l & 15, lg = l >> 4;

  f32x4 acc[8];
#pragma unroll
  for (int ct = 0; ct < 8; ct++) acc[ct] = f32x4{0.f, 0.f, 0.f, 0.f};

  // ---- Phase A: ks 0..3 straight from hs (global, L2) ----
#pragma unroll
  for (int ks = 0; ks < 4; ks++) {
    int row = row0 + rowoff + lr;
    int rowc = row < N ? row : N - 1;
    const float* src = hs + (size_t)rowc * H + ks * 32 + lg * 8;
    float4 x0 = ((const float4*)src)[0];
    float4 x1 = ((const float4*)src)[1];
    short8 ahi, alo;
    cvt8(x0, x1, ahi, alo);
#pragma unroll
    for (int ct = 0; ct < 8; ct++) {
      int gct = ctoffA + ct;
      short8 bhi = ((const short8*)BAhi)[((ks * 16 + gct) << 6) + l];
      short8 blo = ((const short8*)BAlo)[((ks * 16 + gct) << 6) + l];
      acc[ct] = MFMA16(ahi, bhi, acc[ct]);
      acc[ct] = MFMA16(ahi, blo, acc[ct]);
      acc[ct] = MFMA16(alo, bhi, acc[ct]);
    }
  }
  // ---- Phase A: ks 4 from ext (S/deg/1) ----
  {
    const float* src = &ext[rowoff + lr][lg * 8];
    float4 x0 = ((const float4*)src)[0];
    float4 x1 = ((const float4*)src)[1];
    short8 ahi, alo;
    cvt8(x0, x1, ahi, alo);
#pragma unroll
    for (int ct = 0; ct < 8; ct++) {
      int gct = ctoffA + ct;
      short8 bhi = ((const short8*)BAhi)[((4 * 16 + gct) << 6) + l];
      short8 blo = ((const short8*)BAlo)[((4 * 16 + gct) << 6) + l];
      acc[ct] = MFMA16(ahi, bhi, acc[ct]);
      acc[ct] = MFMA16(ahi, blo, acc[ct]);
      acc[ct] = MFMA16(alo, bhi, acc[ct]);
    }
  }

  // ---- epilogue A: BN + relu, f32 -> bf16 hi/lo into swizzled LDS ----
#pragma unroll
  for (int ct = 0; ct < 8; ct++) {
    int c = (ctoffA + ct) * 16 + lr;
    float scv = cc[c], shv = cc[H2 + c];
#pragma unroll
    for (int r = 0; r < 4; r++) {
      float z = acc[ct][r] * scv + shv;
      z = fmaxf(z, 0.f);
      unsigned short h, lo2;
      f2bf_hilo(z, h, lo2);
      int zr = rowoff + lg * 4 + r;
      unsigned off = (unsigned)(zr * 512 + c * 2) ^ (unsigned)((zr & 7) << 4);
      *(unsigned short*)((char*)zhi + off) = h;
      *(unsigned short*)((char*)zlo + off) = lo2;
    }
  }
  __syncthreads();

  // ---- Phase B: out = z @ w2 ----
  f32x4 acc2[4];
#pragma unroll
  for (int ct = 0; ct < 4; ct++) acc2[ct] = f32x4{0.f, 0.f, 0.f, 0.f};
#pragma unroll
  for (int ks = 0; ks < 8; ks++) {
    int zr = rowoff + lr;
    unsigned off = (unsigned)(zr * 512 + (ks * 32 + lg * 8) * 2) ^ (unsigned)((zr & 7) << 4);
    short8 ahi = *(const short8*)((char*)zhi + off);
    short8 alo = *(const short8*)((char*)zlo + off);
#pragma unroll
    for (int ct = 0; ct < 4; ct++) {
      int gct = (wv & 1) * 4 + ct;
      short8 bhi = ((const short8*)BBhi)[((ks * 8 + gct) << 6) + l];
      short8 blo = ((const short8*)BBlo)[((ks * 8 + gct) << 6) + l];
      acc2[ct] = MFMA16(ahi, bhi, acc2[ct]);
      acc2[ct] = MFMA16(ahi, blo, acc2[ct]);
      acc2[ct] = MFMA16(alo, bhi, acc2[ct]);
    }
  }

  // ---- epilogue B ----
#pragma unroll
  for (int ct = 0; ct < 4; ct++) {
    int c2 = ((wv & 1) * 4 + ct) * 16 + lr;
    float bias = b2[c2];
#pragma unroll
    for (int r = 0; r < 4; r++) {
      int row = row0 + rowoff + lg * 4 + r;
      if (row >= N) continue;
      float val = acc2[ct][r] + bias;
      if (relu_out) val = fmaxf(val, 0.f);
      if (pool) {
        atomicAdd(&out[(size_t)batch[row] * H + c2], val);
      } else {
        out[(size_t)row * H + c2] = val;
      }
    }
  }
}

// ---------------- graph node counts ----------------
__global__ void k_cnt(const int* __restrict__ batch, float* __restrict__ cnt, int N) {
  int v = blockIdx.x * blockDim.x + threadIdx.x;
  if (v < N) atomicAdd(&cnt[batch[v]], 1.0f);
}

// ---------------- prediction head ----------------
__global__ void k_pred(const float* __restrict__ pooled, const float* __restrict__ cnt,
                       const float* __restrict__ pw, const float* __restrict__ pb,
                       float* __restrict__ outp) {
  int g = blockIdx.x;
  int t = threadIdx.x;
  if (t >= NT) return;
  float acc = 0.f;
  for (int k = 0; k < H; k++)
    acc += pooled[(size_t)g * H + k] * (pw[k * NT + t] + pw[(H + k) * NT + t]);
  float c = fmaxf(cnt[g], 1.0f);
  outp[(size_t)g * NT + t] = acc / c + pb[t];
}

extern "C" void kernel_launch(void* const* d_in, const int* in_sizes, int n_in,
                              void* d_out, int out_size, void* d_ws, size_t ws_size,
                              hipStream_t stream) {
  const int*   x     = (const int*)d_in[0];
  const int*   ei    = (const int*)d_in[1];
  const float* ea    = (const float*)d_in[2];
  const int*   batch = (const int*)d_in[3];
  const int*   sli   = (const int*)d_in[4];
  const int*   slt   = (const int*)d_in[5];
  const float* emb   = (const float*)d_in[6];
  const float* encw[2] = {(const float*)d_in[7],  (const float*)d_in[17]};
  const float* encb[2] = {(const float*)d_in[8],  (const float*)d_in[18]};
  const float* w1[2]   = {(const float*)d_in[9],  (const float*)d_in[19]};
  const float* b1[2]   = {(const float*)d_in[10], (const float*)d_in[20]};
  const float* gam[2]  = {(const float*)d_in[11], (const float*)d_in[21]};
  const float* bet[2]  = {(const float*)d_in[12], (const float*)d_in[22]};
  const float* mea[2]  = {(const float*)d_in[13], (const float*)d_in[23]};
  const float* var[2]  = {(const float*)d_in[14], (const float*)d_in[24]};
  const float* w2[2]   = {(const float*)d_in[15], (const float*)d_in[25]};
  const float* b2[2]   = {(const float*)d_in[16], (const float*)d_in[26]};
  const float* pw = (const float*)d_in[27];
  const float* pb = (const float*)d_in[28];

  int N = in_sizes[0];
  int E = in_sizes[1] / 2;

  char* p = (char*)d_ws;
  auto alloc = [&](size_t bytes) {
    char* r = p;
    p += (bytes + 255) / 256 * 256;
    return r;
  };
  unsigned* deg    = (unsigned*)alloc((size_t)N * 4);
  float*    S      = (float*)alloc((size_t)N * NF * 4);
  unsigned* off    = (unsigned*)alloc((size_t)(N + 1) * 4);
  unsigned* cur    = (unsigned*)alloc((size_t)N * 4);
  int*      csrc   = (int*)alloc((size_t)E * 4);
  int*      ceid   = (int*)alloc((size_t)E * 4);
  float*    hA     = (float*)alloc((size_t)N * H * 4);
  float*    hS     = (float*)alloc((size_t)N * H * 4);
  float*    hB     = (float*)alloc((size_t)N * H * 4);
  unsigned short* BAhi = (unsigned short*)alloc((size_t)5 * 16 * 64 * 8 * 2);
  unsigned short* BAlo = (unsigned short*)alloc((size_t)5 * 16 * 64 * 8 * 2);
  unsigned short* BBhi = (unsigned short*)alloc((size_t)8 * 8 * 64 * 8 * 2);
  unsigned short* BBlo = (unsigned short*)alloc((size_t)8 * 8 * 64 * 8 * 2);
  float*    cc     = (float*)alloc((size_t)2 * H2 * 4);
  float*    pooled = (float*)alloc((size_t)NG * H * 4);
  float*    cnt    = (float*)alloc((size_t)NG * 4);

  hipMemsetAsync(deg, 0, (size_t)N * 4, stream);
  hipMemsetAsync(pooled, 0, (size_t)NG * H * 4, stream);
  hipMemsetAsync(cnt, 0, (size_t)NG * 4, stream);

  int nblk = (N + 31) / 32;

  k_h0<<<(N * 32 + 255) / 256, 256, 0, stream>>>(x, emb, hA, N);
  k_deg<<<(E + 255) / 256, 256, 0, stream>>>(ei, deg, E);
  k_scan<<<1, 1024, 0, stream>>>(deg, off, cur, N);
  k_scatter<<<(E + 255) / 256, 256, 0, stream>>>(ei, cur, csrc, ceid, E);
  k_S<<<(N + 31) / 32, 256, 0, stream>>>(ea, off, ceid, S, N);

  // layer 0
  k_prepA<<<1, 256, 0, stream>>>(encw[0], encb[0], w1[0], b1[0], gam[0], bet[0],
                                 mea[0], var[0], sli, slt, BAhi, BAlo, cc);
  k_prepB2<<<1, 256, 0, stream>>>(w2[0], BBhi, BBlo);
  k_gather<<<(N + 3) / 4, 256, 0, stream>>>(hA, off, csrc, hS, N);
  k_layer<<<nblk, 256, 0, stream>>>(hS, S, deg, BAhi, BAlo, BBhi, BBlo, cc, b2[0],
                                    hB, batch, N, 1, 0);
  // layer 1 (pooled output)
  k_prepA<<<1, 256, 0, stream>>>(encw[1], encb[1], w1[1], b1[1], gam[1], bet[1],
                                 mea[1], var[1], sli, slt, BAhi, BAlo, cc);
  k_prepB2<<<1, 256, 0, stream>>>(w2[1], BBhi, BBlo);
  k_gather<<<(N + 3) / 4, 256, 0, stream>>>(hB, off, csrc, hS, N);
  k_layer<<<nblk, 256, 0, stream>>>(hS, S, deg, BAhi, BAlo, BBhi, BBlo, cc, b2[1],
                                    pooled, batch, N, 0, 1);

  k_cnt<<<(N + 255) / 256, 256, 0, stream>>>(batch, cnt, N);
  k_pred<<<NG, 64, 0, stream>>>(pooled, cnt, pw, pb, (float*)d_out);
}

// Round 6
// 679.933 us; speedup vs baseline: 1.2176x; 1.2176x over previous
//
#include <hip/hip_runtime.h>

#define H   128
#define H2  256
#define NG  256
#define NT  40
#define NF  9

typedef __attribute__((ext_vector_type(8))) short short8;
typedef __attribute__((ext_vector_type(4))) float f32x4;

#define MFMA16(a, b, c) __builtin_amdgcn_mfma_f32_16x16x32_bf16(a, b, c, 0, 0, 0)

// float -> bf16 hi + bf16 lo (RNE both), x ~= hi + lo with ~2^-16 rel error
__device__ __forceinline__ void f2bf_hilo(float x, unsigned short& hi, unsigned short& lo) {
  unsigned u = __float_as_uint(x);
  unsigned hh = (u + 0x7FFFu + ((u >> 16) & 1u)) >> 16;
  float hf = __uint_as_float(hh << 16);
  float r = x - hf;
  unsigned v = __float_as_uint(r);
  unsigned ll = (v + 0x7FFFu + ((v >> 16) & 1u)) >> 16;
  hi = (unsigned short)hh;
  lo = (unsigned short)ll;
}

__device__ __forceinline__ void cvt8(float4 a, float4 b, short8& hi, short8& lo) {
  float xs[8] = {a.x, a.y, a.z, a.w, b.x, b.y, b.z, b.w};
#pragma unroll
  for (int j = 0; j < 8; j++) {
    unsigned short h, l;
    f2bf_hilo(xs[j], h, l);
    hi[j] = (short)h;
    lo[j] = (short)l;
  }
}

// ---------------- packed degree (lo16) + count of x[src]==1 (hi16) ----------------
__global__ void k_degc(const int* __restrict__ ei, const int* __restrict__ x,
                       unsigned* __restrict__ degc, int E) {
  int e = blockIdx.x * blockDim.x + threadIdx.x;
  if (e >= E) return;
  int dst = ei[e], src = ei[E + e];
  atomicAdd(&degc[dst], 1u + ((unsigned)x[src] << 16));
}

// ---------------- exclusive scan of deg -> off, cur ----------------
__global__ __launch_bounds__(1024) void k_scan(const unsigned* __restrict__ degc,
                                               unsigned* __restrict__ off,
                                               unsigned* __restrict__ cur, int N) {
  __shared__ unsigned wsum[16];
  __shared__ unsigned wpre[16];
  __shared__ unsigned s_run;
  int tid = threadIdx.x;
  int lane = tid & 63, wv = tid >> 6;
  if (tid == 0) s_run = 0u;
  __syncthreads();
  for (int base = 0; base < N; base += 4096) {
    int i0 = base + tid * 4;
    unsigned v0 = 0, v1 = 0, v2 = 0, v3 = 0;
    if (i0 + 0 < N) v0 = degc[i0 + 0] & 0xFFFFu;
    if (i0 + 1 < N) v1 = degc[i0 + 1] & 0xFFFFu;
    if (i0 + 2 < N) v2 = degc[i0 + 2] & 0xFFFFu;
    if (i0 + 3 < N) v3 = degc[i0 + 3] & 0xFFFFu;
    unsigned tsum = v0 + v1 + v2 + v3;
    unsigned sc = tsum;
#pragma unroll
    for (int d = 1; d < 64; d <<= 1) {
      unsigned t = __shfl_up(sc, d);
      if (lane >= d) sc += t;
    }
    if (lane == 63) wsum[wv] = sc;
    __syncthreads();
    if (wv == 0 && lane < 16) {
      unsigned xv = wsum[lane];
#pragma unroll
      for (int d = 1; d < 16; d <<= 1) {
        unsigned t = __shfl_up(xv, d);
        if (lane >= d) xv += t;
      }
      wpre[lane] = xv;
    }
    __syncthreads();
    unsigned excl = s_run + (wv ? wpre[wv - 1] : 0u) + (sc - tsum);
    unsigned p1 = excl + v0, p2 = p1 + v1, p3 = p2 + v2;
    if (i0 + 0 < N) { off[i0 + 0] = excl; cur[i0 + 0] = excl; }
    if (i0 + 1 < N) { off[i0 + 1] = p1;   cur[i0 + 1] = p1; }
    if (i0 + 2 < N) { off[i0 + 2] = p2;   cur[i0 + 2] = p2; }
    if (i0 + 3 < N) { off[i0 + 3] = p3;   cur[i0 + 3] = p3; }
    __syncthreads();
    if (tid == 0) s_run += wpre[15];
  }
  if (tid == 0) off[N] = s_run;
}

// ---------------- scatter edge src + edge id into CSR ----------------
__global__ void k_scatter(const int* __restrict__ ei, unsigned* __restrict__ cur,
                          int* __restrict__ csrc, int* __restrict__ ceid, int E) {
  int e = blockIdx.x * blockDim.x + threadIdx.x;
  if (e >= E) return;
  int dst = ei[e], src = ei[E + e];
  unsigned pos = atomicAdd(&cur[dst], 1u);
  csrc[pos] = src;
  ceid[pos] = e;
}

// ---------------- S[v] = sum of ea rows of incoming edges ----------------
__global__ __launch_bounds__(256) void k_S(const float* __restrict__ ea,
    const unsigned* __restrict__ off, const int* __restrict__ ceid,
    float* __restrict__ S, int N) {
  int lane = threadIdx.x & 63;
  int wv = threadIdx.x >> 6;
  int sub = lane & 7;
  int v = blockIdx.x * 32 + wv * 8 + (lane >> 3);
  if (v >= N) return;
  unsigned o = off[v], e = off[v + 1];
  float acc[NF];
#pragma unroll
  for (int f = 0; f < NF; f++) acc[f] = 0.f;
  for (unsigned i = o + sub; i < e; i += 8) {
    const float* a = ea + (size_t)ceid[i] * NF;
#pragma unroll
    for (int f = 0; f < NF; f++) acc[f] += a[f];
  }
#pragma unroll
  for (int d = 1; d < 8; d <<= 1)
#pragma unroll
    for (int f = 0; f < NF; f++) acc[f] += __shfl_xor(acc[f], d);
  if (sub == 0) {
#pragma unroll
    for (int f = 0; f < NF; f++) S[(size_t)v * NF + f] = acc[f];
  }
}

// ---------------- hsum[v] = h[v] + sum_{incoming} h[src], 4x unrolled ----------------
__global__ __launch_bounds__(256) void k_gather(const float* __restrict__ h,
    const unsigned* __restrict__ off, const int* __restrict__ csrc,
    float* __restrict__ hs, int N) {
  int v = blockIdx.x * 4 + (threadIdx.x >> 6);
  int lane = threadIdx.x & 63;
  if (v >= N) return;
  unsigned o = off[v], e = off[v + 1];
  const float2* hp = (const float2*)h;
  float2 acc = hp[(size_t)v * 64 + lane];
  float2 a0 = {0.f, 0.f}, a1 = {0.f, 0.f}, a2 = {0.f, 0.f}, a3 = {0.f, 0.f};
  unsigned i = o;
  for (; i + 4 <= e; i += 4) {
    int s0 = csrc[i], s1 = csrc[i + 1], s2 = csrc[i + 2], s3 = csrc[i + 3];
    float2 t0 = hp[(size_t)s0 * 64 + lane];
    float2 t1 = hp[(size_t)s1 * 64 + lane];
    float2 t2 = hp[(size_t)s2 * 64 + lane];
    float2 t3 = hp[(size_t)s3 * 64 + lane];
    a0.x += t0.x; a0.y += t0.y;
    a1.x += t1.x; a1.y += t1.y;
    a2.x += t2.x; a2.y += t2.y;
    a3.x += t3.x; a3.y += t3.y;
  }
  for (; i < e; i++) {
    float2 t = hp[(size_t)csrc[i] * 64 + lane];
    acc.x += t.x; acc.y += t.y;
  }
  acc.x += (a0.x + a1.x) + (a2.x + a3.x);
  acc.y += (a0.y + a1.y) + (a2.y + a3.y);
  ((float2*)hs)[(size_t)v * 64 + lane] = acc;
}

// frag idx for (k,c): ks=k>>5, ct=c>>4, lane=((k&31)>>3)*16+(c&15), j=k&7
// ---------------- layer-0 B' (32x256): rank-2 h0 collapse ----------------
// rows: 0=e0=emb0@W1top, 1=e1=emb1@W1top, 2-10=M, 11=u, 12=K0, 13-31=0
__global__ void k_prepA0(const float* __restrict__ emb,
                         const float* __restrict__ enc_w, const float* __restrict__ enc_b,
                         const float* __restrict__ w1, const float* __restrict__ b1,
                         const float* __restrict__ gamma, const float* __restrict__ beta,
                         const float* __restrict__ mean, const float* __restrict__ var,
                         const int* __restrict__ sli, const int* __restrict__ slt,
                         unsigned short* __restrict__ BAhi, unsigned short* __restrict__ BAlo,
                         float* __restrict__ cc) {
  int c = threadIdx.x;  // 256
  float e0 = 0.f, e1 = 0.f, u = 0.f;
  float m[NF];
#pragma unroll
  for (int f = 0; f < NF; f++) m[f] = 0.f;
  for (int k = 0; k < H; k++) {
    float wt = w1[(size_t)k * H2 + c];
    e0 += emb[k] * wt;
    e1 += emb[H + k] * wt;
    float wb = w1[(size_t)(H + k) * H2 + c];
#pragma unroll
    for (int f = 0; f < NF; f++) m[f] += enc_w[f * H + k] * wb;
    u += enc_b[k] * wb;
  }
  float k0 = (float)(*slt) * m[*sli] + u + b1[c];
  float scv = gamma[c] * rsqrtf(var[c] + 1e-5f);
  cc[c] = scv;
  cc[H2 + c] = beta[c] - mean[c] * scv;
  int ct = c >> 4, cl = c & 15;
  for (int k = 0; k < 32; k++) {
    float val;
    if (k == 0)       val = e0;
    else if (k == 1)  val = e1;
    else if (k < 11)  val = m[k - 2];
    else if (k == 11) val = u;
    else if (k == 12) val = k0;
    else              val = 0.f;
    unsigned short h, l;
    f2bf_hilo(val, h, l);
    int lane = (k >> 3) * 16 + cl, j = k & 7;
    size_t idx = ((size_t)(ct * 64 + lane)) * 8 + j;
    BAhi[idx] = h;
    BAlo[idx] = l;
  }
}

// ---------------- layer-1 B' (160x256) ----------------
// rows: 0-127 w1_top, 128-136 M, 137 u, 138 K0, 139-159 zero
__global__ void k_prepA1(const float* __restrict__ enc_w, const float* __restrict__ enc_b,
                         const float* __restrict__ w1, const float* __restrict__ b1,
                         const float* __restrict__ gamma, const float* __restrict__ beta,
                         const float* __restrict__ mean, const float* __restrict__ var,
                         const int* __restrict__ sli, const int* __restrict__ slt,
                         unsigned short* __restrict__ BAhi, unsigned short* __restrict__ BAlo,
                         float* __restrict__ cc) {
  int c = threadIdx.x;  // 256
  float m[NF];
  float u = 0.f;
#pragma unroll
  for (int f = 0; f < NF; f++) m[f] = 0.f;
  for (int k = 0; k < H; k++) {
    float wv = w1[(size_t)(H + k) * H2 + c];
#pragma unroll
    for (int f = 0; f < NF; f++) m[f] += enc_w[f * H + k] * wv;
    u += enc_b[k] * wv;
  }
  float k0 = (float)(*slt) * m[*sli] + u + b1[c];
  float scv = gamma[c] * rsqrtf(var[c] + 1e-5f);
  cc[c] = scv;
  cc[H2 + c] = beta[c] - mean[c] * scv;
  int ct = c >> 4, cl = c & 15;
  for (int k = 0; k < 160; k++) {
    float val;
    if (k < 128)      val = w1[(size_t)k * H2 + c];
    else if (k < 137) val = m[k - 128];
    else if (k == 137) val = u;
    else if (k == 138) val = k0;
    else              val = 0.f;
    unsigned short h, l;
    f2bf_hilo(val, h, l);
    int ks = k >> 5, kr = k & 31;
    int lane = (kr >> 3) * 16 + cl, j = kr & 7;
    size_t idx = ((size_t)((ks * 16 + ct) * 64 + lane)) * 8 + j;
    BAhi[idx] = h;
    BAlo[idx] = l;
  }
}

// ---------------- fragment-ordered bf16 hi/lo of w2 (256x128) ----------------
__global__ void k_prepB2(const float* __restrict__ w2,
                         unsigned short* __restrict__ BBhi, unsigned short* __restrict__ BBlo) {
  int t = threadIdx.x;  // 256
  int c = t & 127, half = t >> 7;
  int ct = c >> 4, cl = c & 15;
  for (int kk = 0; kk < 128; kk++) {
    int k = half * 128 + kk;
    float val = w2[(size_t)k * H + c];
    unsigned short h, l;
    f2bf_hilo(val, h, l);
    int ks = k >> 5, kr = k & 31;
    int lane = (kr >> 3) * 16 + cl, j = kr & 7;
    size_t idx = ((size_t)((ks * 8 + ct) * 64 + lane)) * 8 + j;
    BBhi[idx] = h;
    BBlo[idx] = l;
  }
}

// ---------------- fused MFMA GIN layer ----------------
// nks=0 (layer0): A = [a0,a1,S,deg,1] (K=32, ext only)
// nks=4 (layer1): A = [hs | S,deg,1]  (K=160)
__global__ __launch_bounds__(256) void k_layer(
    const float* __restrict__ hs, const float* __restrict__ S,
    const unsigned* __restrict__ degc, const int* __restrict__ x,
    const unsigned short* __restrict__ BAhi, const unsigned short* __restrict__ BAlo,
    const unsigned short* __restrict__ BBhi, const unsigned short* __restrict__ BBlo,
    const float* __restrict__ cc, const float* __restrict__ b2,
    float* __restrict__ out, const int* __restrict__ batch,
    int N, int relu_out, int pool, int nks) {
  __shared__ float ext[32][36];
  __shared__ unsigned short zhi[32 * 256];
  __shared__ unsigned short zlo[32 * 256];
  int tid = threadIdx.x;
  int row0 = blockIdx.x * 32;

  for (int i = tid; i < 32 * 36; i += 256) {
    int r = i / 36, c2 = i - r * 36;
    int v = row0 + r;
    float val = 0.f;
    if (v < N) {
      unsigned pk = degc[v];
      float dg = (float)(pk & 0xFFFFu);
      float c1 = (float)(pk >> 16);
      if (nks == 0) {
        if (c2 == 0)       val = (dg - c1) + ((x[v] == 0) ? 1.f : 0.f);
        else if (c2 == 1)  val = c1 + ((x[v] != 0) ? 1.f : 0.f);
        else if (c2 < 11)  val = S[(size_t)v * NF + (c2 - 2)];
        else if (c2 == 11) val = dg;
        else if (c2 == 12) val = 1.0f;
      } else {
        if (c2 < NF)       val = S[(size_t)v * NF + c2];
        else if (c2 == 9)  val = dg;
        else if (c2 == 10) val = 1.0f;
      }
    }
    ext[r][c2] = val;
  }
  __syncthreads();

  int l = tid & 63, wv = tid >> 6;
  int rowoff = (wv >> 1) * 16;
  int ctoffA = (wv & 1) * 8;
  int lr = l & 15, lg = l >> 4;

  f32x4 acc[8];
#pragma unroll
  for (int ct = 0; ct < 8; ct++) acc[ct] = f32x4{0.f, 0.f, 0.f, 0.f};

  // ---- Phase A: hs k-steps (layer1 only) ----
  if (nks) {
#pragma unroll
    for (int ks = 0; ks < 4; ks++) {
      int row = row0 + rowoff + lr;
      int rowc = row < N ? row : N - 1;
      const float* src = hs + (size_t)rowc * H + ks * 32 + lg * 8;
      float4 x0 = ((const float4*)src)[0];
      float4 x1 = ((const float4*)src)[1];
      short8 ahi, alo;
      cvt8(x0, x1, ahi, alo);
#pragma unroll
      for (int ct = 0; ct < 8; ct++) {
        int gct = ctoffA + ct;
        short8 bhi = ((const short8*)BAhi)[((ks * 16 + gct) << 6) + l];
        short8 blo = ((const short8*)BAlo)[((ks * 16 + gct) << 6) + l];
        acc[ct] = MFMA16(ahi, bhi, acc[ct]);
        acc[ct] = MFMA16(ahi, blo, acc[ct]);
        acc[ct] = MFMA16(alo, bhi, acc[ct]);
      }
    }
  }
  // ---- Phase A: ext k-step (frag slice nks) ----
  {
    const float* src = &ext[rowoff + lr][lg * 8];
    float4 x0 = ((const float4*)src)[0];
    float4 x1 = ((const float4*)src)[1];
    short8 ahi, alo;
    cvt8(x0, x1, ahi, alo);
#pragma unroll
    for (int ct = 0; ct < 8; ct++) {
      int gct = ctoffA + ct;
      short8 bhi = ((const short8*)BAhi)[((nks * 16 + gct) << 6) + l];
      short8 blo = ((const short8*)BAlo)[((nks * 16 + gct) << 6) + l];
      acc[ct] = MFMA16(ahi, bhi, acc[ct]);
      acc[ct] = MFMA16(ahi, blo, acc[ct]);
      acc[ct] = MFMA16(alo, bhi, acc[ct]);
    }
  }

  // ---- epilogue A: BN + relu -> bf16 hi/lo swizzled LDS ----
#pragma unroll
  for (int ct = 0; ct < 8; ct++) {
    int c = (ctoffA + ct) * 16 + lr;
    float scv = cc[c], shv = cc[H2 + c];
#pragma unroll
    for (int r = 0; r < 4; r++) {
      float z = acc[ct][r] * scv + shv;
      z = fmaxf(z, 0.f);
      unsigned short h, lo2;
      f2bf_hilo(z, h, lo2);
      int zr = rowoff + lg * 4 + r;
      unsigned off = (unsigned)(zr * 512 + c * 2) ^ (unsigned)((zr & 7) << 4);
      *(unsigned short*)((char*)zhi + off) = h;
      *(unsigned short*)((char*)zlo + off) = lo2;
    }
  }
  __syncthreads();

  // ---- Phase B: out = z @ w2 ----
  f32x4 acc2[4];
#pragma unroll
  for (int ct = 0; ct < 4; ct++) acc2[ct] = f32x4{0.f, 0.f, 0.f, 0.f};
#pragma unroll
  for (int ks = 0; ks < 8; ks++) {
    int zr = rowoff + lr;
    unsigned off = (unsigned)(zr * 512 + (ks * 32 + lg * 8) * 2) ^ (unsigned)((zr & 7) << 4);
    short8 ahi = *(const short8*)((char*)zhi + off);
    short8 alo = *(const short8*)((char*)zlo + off);
#pragma unroll
    for (int ct = 0; ct < 4; ct++) {
      int gct = (wv & 1) * 4 + ct;
      short8 bhi = ((const short8*)BBhi)[((ks * 8 + gct) << 6) + l];
      short8 blo = ((const short8*)BBlo)[((ks * 8 + gct) << 6) + l];
      acc2[ct] = MFMA16(ahi, bhi, acc2[ct]);
      acc2[ct] = MFMA16(ahi, blo, acc2[ct]);
      acc2[ct] = MFMA16(alo, bhi, acc2[ct]);
    }
  }

  // ---- epilogue B ----
#pragma unroll
  for (int ct = 0; ct < 4; ct++) {
    int c2 = ((wv & 1) * 4 + ct) * 16 + lr;
    float bias = b2[c2];
#pragma unroll
    for (int r = 0; r < 4; r++) {
      int row = row0 + rowoff + lg * 4 + r;
      if (row >= N) continue;
      float val = acc2[ct][r] + bias;
      if (relu_out) val = fmaxf(val, 0.f);
      if (pool) {
        atomicAdd(&out[(size_t)batch[row] * H + c2], val);
      } else {
        out[(size_t)row * H + c2] = val;
      }
    }
  }
}

// ---------------- graph node counts ----------------
__global__ void k_cnt(const int* __restrict__ batch, float* __restrict__ cnt, int N) {
  int v = blockIdx.x * blockDim.x + threadIdx.x;
  if (v < N) atomicAdd(&cnt[batch[v]], 1.0f);
}

// ---------------- prediction head ----------------
__global__ void k_pred(const float* __restrict__ pooled, const float* __restrict__ cnt,
                       const float* __restrict__ pw, const float* __restrict__ pb,
                       float* __restrict__ outp) {
  int g = blockIdx.x;
  int t = threadIdx.x;
  if (t >= NT) return;
  float acc = 0.f;
  for (int k = 0; k < H; k++)
    acc += pooled[(size_t)g * H + k] * (pw[k * NT + t] + pw[(H + k) * NT + t]);
  float c = fmaxf(cnt[g], 1.0f);
  outp[(size_t)g * NT + t] = acc / c + pb[t];
}

extern "C" void kernel_launch(void* const* d_in, const int* in_sizes, int n_in,
                              void* d_out, int out_size, void* d_ws, size_t ws_size,
                              hipStream_t stream) {
  const int*   x     = (const int*)d_in[0];
  const int*   ei    = (const int*)d_in[1];
  const float* ea    = (const float*)d_in[2];
  const int*   batch = (const int*)d_in[3];
  const int*   sli   = (const int*)d_in[4];
  const int*   slt   = (const int*)d_in[5];
  const float* emb   = (const float*)d_in[6];
  const float* encw[2] = {(const float*)d_in[7],  (const float*)d_in[17]};
  const float* encb[2] = {(const float*)d_in[8],  (const float*)d_in[18]};
  const float* w1[2]   = {(const float*)d_in[9],  (const float*)d_in[19]};
  const float* b1[2]   = {(const float*)d_in[10], (const float*)d_in[20]};
  const float* gam[2]  = {(const float*)d_in[11], (const float*)d_in[21]};
  const float* bet[2]  = {(const float*)d_in[12], (const float*)d_in[22]};
  const float* mea[2]  = {(const float*)d_in[13], (const float*)d_in[23]};
  const float* var[2]  = {(const float*)d_in[14], (const float*)d_in[24]};
  const float* w2[2]   = {(const float*)d_in[15], (const float*)d_in[25]};
  const float* b2[2]   = {(const float*)d_in[16], (const float*)d_in[26]};
  const float* pw = (const float*)d_in[27];
  const float* pb = (const float*)d_in[28];

  int N = in_sizes[0];
  int E = in_sizes[1] / 2;

  char* p = (char*)d_ws;
  auto alloc = [&](size_t bytes) {
    char* r = p;
    p += (bytes + 255) / 256 * 256;
    return r;
  };
  unsigned* degc   = (unsigned*)alloc((size_t)N * 4);
  float*    S      = (float*)alloc((size_t)N * NF * 4);
  unsigned* off    = (unsigned*)alloc((size_t)(N + 1) * 4);
  unsigned* cur    = (unsigned*)alloc((size_t)N * 4);
  int*      csrc   = (int*)alloc((size_t)E * 4);
  int*      ceid   = (int*)alloc((size_t)E * 4);
  float*    hB     = (float*)alloc((size_t)N * H * 4);
  float*    hS     = (float*)alloc((size_t)N * H * 4);
  unsigned short* BA0hi = (unsigned short*)alloc((size_t)16 * 64 * 8 * 2);
  unsigned short* BA0lo = (unsigned short*)alloc((size_t)16 * 64 * 8 * 2);
  unsigned short* BA1hi = (unsigned short*)alloc((size_t)5 * 16 * 64 * 8 * 2);
  unsigned short* BA1lo = (unsigned short*)alloc((size_t)5 * 16 * 64 * 8 * 2);
  unsigned short* BB0hi = (unsigned short*)alloc((size_t)8 * 8 * 64 * 8 * 2);
  unsigned short* BB0lo = (unsigned short*)alloc((size_t)8 * 8 * 64 * 8 * 2);
  unsigned short* BB1hi = (unsigned short*)alloc((size_t)8 * 8 * 64 * 8 * 2);
  unsigned short* BB1lo = (unsigned short*)alloc((size_t)8 * 8 * 64 * 8 * 2);
  float*    cc0    = (float*)alloc((size_t)2 * H2 * 4);
  float*    cc1    = (float*)alloc((size_t)2 * H2 * 4);
  float*    pooled = (float*)alloc((size_t)NG * H * 4);
  float*    cnt    = (float*)alloc((size_t)NG * 4);

  hipMemsetAsync(degc, 0, (size_t)N * 4, stream);
  hipMemsetAsync(pooled, 0, (size_t)NG * H * 4, stream);
  hipMemsetAsync(cnt, 0, (size_t)NG * 4, stream);

  int nblk = (N + 31) / 32;

  k_degc<<<(E + 255) / 256, 256, 0, stream>>>(ei, x, degc, E);
  k_scan<<<1, 1024, 0, stream>>>(degc, off, cur, N);
  k_scatter<<<(E + 255) / 256, 256, 0, stream>>>(ei, cur, csrc, ceid, E);
  k_S<<<(N + 31) / 32, 256, 0, stream>>>(ea, off, ceid, S, N);

  k_prepA0<<<1, 256, 0, stream>>>(emb, encw[0], encb[0], w1[0], b1[0], gam[0], bet[0],
                                  mea[0], var[0], sli, slt, BA0hi, BA0lo, cc0);
  k_prepB2<<<1, 256, 0, stream>>>(w2[0], BB0hi, BB0lo);
  k_prepA1<<<1, 256, 0, stream>>>(encw[1], encb[1], w1[1], b1[1], gam[1], bet[1],
                                  mea[1], var[1], sli, slt, BA1hi, BA1lo, cc1);
  k_prepB2<<<1, 256, 0, stream>>>(w2[1], BB1hi, BB1lo);

  // layer 0: no gather, K=32 (rank-2 h0 collapse)
  k_layer<<<nblk, 256, 0, stream>>>(nullptr, S, degc, x, BA0hi, BA0lo, BB0hi, BB0lo,
                                    cc0, b2[0], hB, batch, N, 1, 0, 0);
  // layer 1
  k_gather<<<(N + 3) / 4, 256, 0, stream>>>(hB, off, csrc, hS, N);
  k_layer<<<nblk, 256, 0, stream>>>(hS, S, degc, x, BA1hi, BA1lo, BB1hi, BB1lo,
                                    cc1, b2[1], pooled, batch, N, 0, 1, 4);

  k_cnt<<<(N + 255) / 256, 256, 0, stream>>>(batch, cnt, N);
  k_pred<<<NG, 64, 0, stream>>>(pooled, cnt, pw, pb, (float*)d_out);
}